// Round 4
// baseline (789.470 us; speedup 1.0000x reference)
//
#include <hip/hip_runtime.h>
#include <math.h>

#define NN 100000
#define NE 3200000
#define FIN 512
#define HID 16
#define NC 40

#define NB 782            // buckets of 128 dst nodes (dst>>7); 781*128=99968
#define CAP 4608          // per-bucket slots: mean 4092, sd~64 -> +8 sigma
#define TILE_A 8192
#define GRID_A ((NE + TILE_A - 1) / TILE_A)   // 391

typedef short bf16x8 __attribute__((ext_vector_type(8)));
typedef float f32x4  __attribute__((ext_vector_type(4)));

__device__ inline short bf1(float f) {            // fp32 -> bf16 RNE
    unsigned u = __float_as_uint(f);
    unsigned r = (u + 0x7fffu + ((u >> 16) & 1u)) >> 16;
    return (short)r;
}
__device__ inline bf16x8 pack8(float4 a, float4 b) {
    bf16x8 r;
    r[0] = bf1(a.x); r[1] = bf1(a.y); r[2] = bf1(a.z); r[3] = bf1(a.w);
    r[4] = bf1(b.x); r[5] = bf1(b.y); r[6] = bf1(b.z); r[7] = bf1(b.w);
    return r;
}

// ------------------------------------------------------------ init ----------
__global__ __launch_bounds__(256) void k_initgcur(unsigned* __restrict__ gcur) {
    int b = blockIdx.x * 256 + threadIdx.x;
    if (b < NB) gcur[b] = (unsigned)b * CAP;
}

// ---------------------------------------------- pass A: bucket the edges ----
// packed[pos] = (src<<7) | (dst&127), bucketed by dst>>7.
__global__ __launch_bounds__(256) void k_bin(const int* __restrict__ src,
                                             const int* __restrict__ dst,
                                             unsigned* __restrict__ gcur,
                                             unsigned* __restrict__ buf) {
    __shared__ int hist[NB];
    __shared__ unsigned cur[NB];
    const int t = threadIdx.x;
    const int e0 = blockIdx.x * TILE_A;
    const int e1 = (e0 + TILE_A < NE) ? e0 + TILE_A : NE;

    for (int b = t; b < NB; b += 256) hist[b] = 0;
    __syncthreads();
    for (int e = e0 + t; e < e1; e += 256)
        atomicAdd(&hist[dst[e] >> 7], 1);
    __syncthreads();
    for (int b = t; b < NB; b += 256)
        if (hist[b]) cur[b] = atomicAdd(&gcur[b], (unsigned)hist[b]);
    __syncthreads();
    for (int e = e0 + t; e < e1; e += 256) {
        int d = dst[e];
        int b = d >> 7;
        unsigned pos = atomicAdd(&cur[b], 1u);
        if (pos < (unsigned)(b + 1) * CAP)            // overflow guard (~0 prob)
            buf[pos] = ((unsigned)src[e] << 7) | (unsigned)(d & 127);
    }
}

// ------------------------------- pass B1: per-bucket degree -> dinv ---------
__global__ __launch_bounds__(256) void k_deg(const unsigned* __restrict__ gcur,
                                             const unsigned* __restrict__ buf,
                                             float* __restrict__ dinv) {
    __shared__ int deg[128];
    const int b = blockIdx.x;
    const int t = threadIdx.x;
    const unsigned base = (unsigned)b * CAP;
    int count = (int)(gcur[b] - base);
    if (count > CAP) count = CAP;

    if (t < 128) deg[t] = 0;
    __syncthreads();
    for (int i = t; i < count; i += 256)
        atomicAdd(&deg[buf[base + i] & 127u], 1);
    __syncthreads();
    if (t < 128) {
        int n = (b << 7) + t;
        if (n < NN) dinv[n] = rsqrtf(1.0f + (float)deg[t]);  // +1 self loop
    }
}

// ------------------------------------- layer1+Wg: per-wave MFMA GEMM --------
// wave handles 16 nodes: h1 = relu(x@W1^T + b1); h2 = h1@Wg^T;
// writes hs = h2 * dinv (pre-scaled messages).
__global__ __launch_bounds__(256) void k_h2(const float* __restrict__ x,
                                            const float* __restrict__ W1,
                                            const float* __restrict__ b1,
                                            const float* __restrict__ Wg,
                                            const float* __restrict__ dinv,
                                            float* __restrict__ hs) {
    const int lane = threadIdx.x & 63;
    const int wv   = threadIdx.x >> 6;          // 0..3
    const int c    = lane & 15;                 // A row / B col
    const int q    = lane >> 4;                 // 0..3
    const int n0   = blockIdx.x * 64 + wv * 16;

    bf16x8 bf[16];
    const float* wrow = W1 + c * FIN;
#pragma unroll
    for (int kk = 0; kk < 16; ++kk) {
        const float4* p = (const float4*)(wrow + kk * 32 + q * 8);
        bf[kk] = pack8(p[0], p[1]);
    }
    bf16x8 gf = {0,0,0,0,0,0,0,0};
    if (q < 2) {
        const float4* p = (const float4*)(Wg + c * HID + q * 8);
        gf = pack8(p[0], p[1]);
    }

    f32x4 acc = {0.f, 0.f, 0.f, 0.f};
    int na = n0 + c; if (na > NN - 1) na = NN - 1;   // clamp (stores masked)
    const float* xr = x + (size_t)na * FIN + q * 8;
#pragma unroll 4
    for (int kk = 0; kk < 16; ++kk) {
        const float4* p = (const float4*)(xr + kk * 32);
        bf16x8 af = pack8(p[0], p[1]);
        acc = __builtin_amdgcn_mfma_f32_16x16x32_bf16(af, bf[kk], acc, 0, 0, 0);
    }

    __shared__ __align__(16) short tl[4][16][16];
    const float bj = b1[c];
#pragma unroll
    for (int r = 0; r < 4; ++r)
        tl[wv][q * 4 + r][c] = bf1(fmaxf(acc[r] + bj, 0.f));
    __syncthreads();

    bf16x8 a2 = {0,0,0,0,0,0,0,0};
    if (q < 2) a2 = *(const bf16x8*)&tl[wv][c][q * 8];
    f32x4 z = {0.f, 0.f, 0.f, 0.f};
    f32x4 o = __builtin_amdgcn_mfma_f32_16x16x32_bf16(a2, gf, z, 0, 0, 0);
#pragma unroll
    for (int r = 0; r < 4; ++r) {
        int node = n0 + q * 4 + r;
        if (node < NN) hs[node * HID + c] = o[r] * dinv[node];
    }
}

// --------------------- pass B2: per-bucket LDS aggregation ------------------
// acc[ld][f] += hs[src][f] for the bucket's edges; then
// hagg = dinv * (acc + hs_self), written into the bucket's own buf region.
__global__ __launch_bounds__(256) void k_agg(const unsigned* __restrict__ gcur,
                                             unsigned* __restrict__ buf,
                                             const float* __restrict__ dinv,
                                             const float* __restrict__ hs) {
    __shared__ float acc[128 * HID];            // 8 KB
    const int b = blockIdx.x;
    const int t = threadIdx.x;
    const unsigned base = (unsigned)b * CAP;
    int count = (int)(gcur[b] - base);
    if (count > CAP) count = CAP;

    for (int i = t; i < 128 * HID; i += 256) acc[i] = 0.0f;
    __syncthreads();

    const int g = t >> 4;                       // edge group 0..15
    const int f = t & 15;
    for (int i = g; i < count; i += 16) {
        unsigned p = buf[base + i];
        int s  = (int)(p >> 7);
        int ld = (int)(p & 127u);
        atomicAdd(&acc[(ld << 4) + f], hs[(s << 4) + f]);
    }
    __syncthreads();

    float* hout = (float*)buf;
    for (int i = t; i < 128 * HID; i += 256) {
        int ln = i >> 4, ff = i & 15;
        int n = (b << 7) + ln;
        if (n < NN)
            hout[base + i] = dinv[n] * (acc[i] + hs[(n << 4) + ff]);
    }
}

// --------------------------------------- classifier + log_softmax -----------
__global__ __launch_bounds__(256) void k_final(const float* __restrict__ hbuf,
                                               const float* __restrict__ bg,
                                               const float* __restrict__ W2,
                                               const float* __restrict__ b2,
                                               float* __restrict__ out) {
    int n = blockIdx.x * 256 + threadIdx.x;
    if (n >= NN) return;

    const float* hp = hbuf + (size_t)(n >> 7) * CAP + ((n & 127) << 4);
    float v[HID];
    const float4* ap = (const float4*)hp;
#pragma unroll
    for (int qq = 0; qq < 4; ++qq) {
        float4 a = ap[qq];
        v[4*qq+0] = a.x; v[4*qq+1] = a.y; v[4*qq+2] = a.z; v[4*qq+3] = a.w;
    }
#pragma unroll
    for (int j = 0; j < HID; ++j) v[j] = fmaxf(v[j] + bg[j], 0.0f);

    float lg[NC];
    float m = -1e30f;
#pragma unroll
    for (int cc = 0; cc < NC; ++cc) {
        float s = b2[cc];
#pragma unroll
        for (int j = 0; j < HID; ++j) s = fmaf(v[j], W2[cc * HID + j], s);
        lg[cc] = s;
        m = fmaxf(m, s);
    }
    float se = 0.0f;
#pragma unroll
    for (int cc = 0; cc < NC; ++cc) se += expf(lg[cc] - m);
    const float lse = m + logf(se);

    float4* op = (float4*)(out + (size_t)n * NC);
#pragma unroll
    for (int qq = 0; qq < NC / 4; ++qq)
        op[qq] = make_float4(lg[4*qq+0] - lse, lg[4*qq+1] - lse,
                             lg[4*qq+2] - lse, lg[4*qq+3] - lse);
}

// ---------------------------------------------------------------- launch ----
extern "C" void kernel_launch(void* const* d_in, const int* in_sizes, int n_in,
                              void* d_out, int out_size, void* d_ws, size_t ws_size,
                              hipStream_t stream) {
    const float* x   = (const float*)d_in[0];
    const int*   ei  = (const int*)d_in[1];     // [2, NE] int32
    const float* W1  = (const float*)d_in[2];
    const float* b1  = (const float*)d_in[3];
    const float* Wg  = (const float*)d_in[4];
    const float* bg  = (const float*)d_in[5];
    const float* W2  = (const float*)d_in[6];
    const float* b2  = (const float*)d_in[7];
    float*       out = (float*)d_out;

    const int* esrc = ei;
    const int* edst = ei + NE;

    // ws layout (4B units): gcur[NB] | dinv[NN] | hs[NN*16] | buf[NB*CAP]
    // total ~ 21.2 MB
    unsigned* gcur = (unsigned*)d_ws;
    float*    dinv = (float*)(gcur + NB);
    float*    hs   = dinv + NN;
    unsigned* buf  = (unsigned*)(hs + (size_t)NN * HID);

    const int nodeBlocks = (NN + 255) / 256;        // 391
    const int h2Blocks   = (NN + 63) / 64;          // 1563

    k_initgcur<<<(NB + 255) / 256, 256, 0, stream>>>(gcur);
    k_bin<<<GRID_A, 256, 0, stream>>>(esrc, edst, gcur, buf);
    k_deg<<<NB, 256, 0, stream>>>(gcur, buf, dinv);
    k_h2<<<h2Blocks, 256, 0, stream>>>(x, W1, b1, Wg, dinv, hs);
    k_agg<<<NB, 256, 0, stream>>>(gcur, buf, dinv, hs);
    k_final<<<nodeBlocks, 256, 0, stream>>>((const float*)buf, bg, W2, b2, out);
}

// Round 5
// 750.755 us; speedup vs baseline: 1.0516x; 1.0516x over previous
//
#include <hip/hip_runtime.h>
#include <math.h>

#define NN 100000
#define NE 3200000
#define FIN 512
#define HID 16
#define NC 40

#define BSH 6             // bucket shift: 64 dst nodes per bucket
#define BSZ 64
#define NB 1563           // ceil(100000/64); 1563*64 = 100032
#define CAP 2304          // mean 2048 + 5.6 sigma (Poisson)
#define TILE_A 8192
#define GRID_A ((NE + TILE_A - 1) / TILE_A)   // 391

typedef short bf16x8 __attribute__((ext_vector_type(8)));
typedef float f32x4  __attribute__((ext_vector_type(4)));

__device__ inline short bf1(float f) {            // fp32 -> bf16 RNE
    unsigned u = __float_as_uint(f);
    unsigned r = (u + 0x7fffu + ((u >> 16) & 1u)) >> 16;
    return (short)r;
}
__device__ inline bf16x8 pack8(float4 a, float4 b) {
    bf16x8 r;
    r[0] = bf1(a.x); r[1] = bf1(a.y); r[2] = bf1(a.z); r[3] = bf1(a.w);
    r[4] = bf1(b.x); r[5] = bf1(b.y); r[6] = bf1(b.z); r[7] = bf1(b.w);
    return r;
}

// ------------------------------------------------------------ init ----------
__global__ __launch_bounds__(256) void k_initgcur(unsigned* __restrict__ gcur) {
    int b = blockIdx.x * 256 + threadIdx.x;
    if (b < NB) gcur[b] = (unsigned)b * CAP;
}

// ---------------------------------------------- pass A: bucket the edges ----
// packed[pos] = (src<<6) | (dst&63), bucketed by dst>>6.
__global__ __launch_bounds__(256) void k_bin(const int* __restrict__ src,
                                             const int* __restrict__ dst,
                                             unsigned* __restrict__ gcur,
                                             unsigned* __restrict__ buf) {
    __shared__ int hist[NB];
    __shared__ unsigned cur[NB];
    const int t = threadIdx.x;
    const int e0 = blockIdx.x * TILE_A;
    const int e1 = (e0 + TILE_A < NE) ? e0 + TILE_A : NE;

    for (int b = t; b < NB; b += 256) hist[b] = 0;
    __syncthreads();
    for (int e = e0 + t; e < e1; e += 256)
        atomicAdd(&hist[dst[e] >> BSH], 1);
    __syncthreads();
    for (int b = t; b < NB; b += 256)
        if (hist[b]) cur[b] = atomicAdd(&gcur[b], (unsigned)hist[b]);
    __syncthreads();
    for (int e = e0 + t; e < e1; e += 256) {
        int d = dst[e];
        int b = d >> BSH;
        unsigned pos = atomicAdd(&cur[b], 1u);
        if (pos < (unsigned)(b + 1) * CAP)            // overflow guard (~0 prob)
            buf[pos] = ((unsigned)src[e] << BSH) | (unsigned)(d & (BSZ - 1));
    }
}

// ------------------------------- pass B1: per-bucket degree -> dinv ---------
__global__ __launch_bounds__(256) void k_deg(const unsigned* __restrict__ gcur,
                                             const unsigned* __restrict__ buf,
                                             float* __restrict__ dinv) {
    __shared__ int deg[BSZ];
    const int b = blockIdx.x;
    const int t = threadIdx.x;
    const unsigned base = (unsigned)b * CAP;
    int count = (int)(gcur[b] - base);
    if (count > CAP) count = CAP;

    if (t < BSZ) deg[t] = 0;
    __syncthreads();
    for (int i = t; i < count; i += 256)
        atomicAdd(&deg[buf[base + i] & (BSZ - 1u)], 1);
    __syncthreads();
    if (t < BSZ) {
        int n = (b << BSH) + t;
        if (n < NN) dinv[n] = rsqrtf(1.0f + (float)deg[t]);  // +1 self loop
    }
}

// ------------------------------------- layer1+Wg: per-wave MFMA GEMM --------
// wave handles 16 nodes: h1 = relu(x@W1^T + b1); h2 = h1@Wg^T;
// writes hs = h2 * dinv (pre-scaled messages).
__global__ __launch_bounds__(256) void k_h2(const float* __restrict__ x,
                                            const float* __restrict__ W1,
                                            const float* __restrict__ b1,
                                            const float* __restrict__ Wg,
                                            const float* __restrict__ dinv,
                                            float* __restrict__ hs) {
    const int lane = threadIdx.x & 63;
    const int wv   = threadIdx.x >> 6;          // 0..3
    const int c    = lane & 15;                 // A row / B col
    const int q    = lane >> 4;                 // 0..3
    const int n0   = blockIdx.x * 64 + wv * 16;

    bf16x8 bf[16];
    const float* wrow = W1 + c * FIN;
#pragma unroll
    for (int kk = 0; kk < 16; ++kk) {
        const float4* p = (const float4*)(wrow + kk * 32 + q * 8);
        bf[kk] = pack8(p[0], p[1]);
    }
    bf16x8 gf = {0,0,0,0,0,0,0,0};
    if (q < 2) {
        const float4* p = (const float4*)(Wg + c * HID + q * 8);
        gf = pack8(p[0], p[1]);
    }

    f32x4 acc = {0.f, 0.f, 0.f, 0.f};
    int na = n0 + c; if (na > NN - 1) na = NN - 1;   // clamp (stores masked)
    const float* xr = x + (size_t)na * FIN + q * 8;
#pragma unroll 4
    for (int kk = 0; kk < 16; ++kk) {
        const float4* p = (const float4*)(xr + kk * 32);
        bf16x8 af = pack8(p[0], p[1]);
        acc = __builtin_amdgcn_mfma_f32_16x16x32_bf16(af, bf[kk], acc, 0, 0, 0);
    }

    __shared__ __align__(16) short tl[4][16][16];
    const float bj = b1[c];
#pragma unroll
    for (int r = 0; r < 4; ++r)
        tl[wv][q * 4 + r][c] = bf1(fmaxf(acc[r] + bj, 0.f));
    __syncthreads();

    bf16x8 a2 = {0,0,0,0,0,0,0,0};
    if (q < 2) a2 = *(const bf16x8*)&tl[wv][c][q * 8];
    f32x4 z = {0.f, 0.f, 0.f, 0.f};
    f32x4 o = __builtin_amdgcn_mfma_f32_16x16x32_bf16(a2, gf, z, 0, 0, 0);
#pragma unroll
    for (int r = 0; r < 4; ++r) {
        int node = n0 + q * 4 + r;
        if (node < NN) hs[node * HID + c] = o[r] * dinv[node];
    }
}

// --------------------- pass B2: per-bucket LDS aggregation ------------------
// lane-per-edge, 2-way unrolled: 64 B hs row gather + 16 padded LDS atomics.
// Output written into the bucket's own (consumed) buf region, coalesced.
__global__ __launch_bounds__(256) void k_agg(const unsigned* __restrict__ gcur,
                                             unsigned* __restrict__ buf,
                                             const float* __restrict__ dinv,
                                             const float* __restrict__ hs) {
    __shared__ float acc[BSZ * 17];             // +1 pad: spread banks
    const int blk = blockIdx.x;
    const int t = threadIdx.x;
    const unsigned base = (unsigned)blk * CAP;
    int count = (int)(gcur[blk] - base);
    if (count > CAP) count = CAP;

    for (int i = t; i < BSZ * 17; i += 256) acc[i] = 0.0f;
    __syncthreads();

    int i = t;
    for (; i + 256 < count; i += 512) {
        unsigned p0 = buf[base + i];
        unsigned p1 = buf[base + i + 256];
        const float4* r0 = (const float4*)(hs + ((size_t)(p0 >> BSH) << 4));
        const float4* r1 = (const float4*)(hs + ((size_t)(p1 >> BSH) << 4));
        float4 a0 = r0[0], b0 = r0[1], c0 = r0[2], d0 = r0[3];
        float4 a1 = r1[0], b1 = r1[1], c1 = r1[2], d1 = r1[3];
        float* q0 = acc + (p0 & (BSZ - 1u)) * 17;
        float* q1 = acc + (p1 & (BSZ - 1u)) * 17;
        atomicAdd(q0 + 0,  a0.x); atomicAdd(q0 + 1,  a0.y);
        atomicAdd(q0 + 2,  a0.z); atomicAdd(q0 + 3,  a0.w);
        atomicAdd(q0 + 4,  b0.x); atomicAdd(q0 + 5,  b0.y);
        atomicAdd(q0 + 6,  b0.z); atomicAdd(q0 + 7,  b0.w);
        atomicAdd(q0 + 8,  c0.x); atomicAdd(q0 + 9,  c0.y);
        atomicAdd(q0 + 10, c0.z); atomicAdd(q0 + 11, c0.w);
        atomicAdd(q0 + 12, d0.x); atomicAdd(q0 + 13, d0.y);
        atomicAdd(q0 + 14, d0.z); atomicAdd(q0 + 15, d0.w);
        atomicAdd(q1 + 0,  a1.x); atomicAdd(q1 + 1,  a1.y);
        atomicAdd(q1 + 2,  a1.z); atomicAdd(q1 + 3,  a1.w);
        atomicAdd(q1 + 4,  b1.x); atomicAdd(q1 + 5,  b1.y);
        atomicAdd(q1 + 6,  b1.z); atomicAdd(q1 + 7,  b1.w);
        atomicAdd(q1 + 8,  c1.x); atomicAdd(q1 + 9,  c1.y);
        atomicAdd(q1 + 10, c1.z); atomicAdd(q1 + 11, c1.w);
        atomicAdd(q1 + 12, d1.x); atomicAdd(q1 + 13, d1.y);
        atomicAdd(q1 + 14, d1.z); atomicAdd(q1 + 15, d1.w);
    }
    if (i < count) {
        unsigned p0 = buf[base + i];
        const float4* r0 = (const float4*)(hs + ((size_t)(p0 >> BSH) << 4));
        float4 a0 = r0[0], b0 = r0[1], c0 = r0[2], d0 = r0[3];
        float* q0 = acc + (p0 & (BSZ - 1u)) * 17;
        atomicAdd(q0 + 0,  a0.x); atomicAdd(q0 + 1,  a0.y);
        atomicAdd(q0 + 2,  a0.z); atomicAdd(q0 + 3,  a0.w);
        atomicAdd(q0 + 4,  b0.x); atomicAdd(q0 + 5,  b0.y);
        atomicAdd(q0 + 6,  b0.z); atomicAdd(q0 + 7,  b0.w);
        atomicAdd(q0 + 8,  c0.x); atomicAdd(q0 + 9,  c0.y);
        atomicAdd(q0 + 10, c0.z); atomicAdd(q0 + 11, c0.w);
        atomicAdd(q0 + 12, d0.x); atomicAdd(q0 + 13, d0.y);
        atomicAdd(q0 + 14, d0.z); atomicAdd(q0 + 15, d0.w);
    }
    __syncthreads();

    float* hout = (float*)buf;
    for (int j = t; j < BSZ * HID; j += 256) {
        int ln = j >> 4, ff = j & 15;
        int n = (blk << BSH) + ln;
        if (n < NN)
            hout[base + j] = dinv[n] * (acc[ln * 17 + ff] + hs[(n << 4) + ff]);
    }
}

// --------------------------------------- classifier + log_softmax -----------
__global__ __launch_bounds__(256) void k_final(const float* __restrict__ hbuf,
                                               const float* __restrict__ bg,
                                               const float* __restrict__ W2,
                                               const float* __restrict__ b2,
                                               float* __restrict__ out) {
    int n = blockIdx.x * 256 + threadIdx.x;
    if (n >= NN) return;

    const float* hp = hbuf + (size_t)(n >> BSH) * CAP + ((n & (BSZ - 1)) << 4);
    float v[HID];
    const float4* ap = (const float4*)hp;
#pragma unroll
    for (int qq = 0; qq < 4; ++qq) {
        float4 a = ap[qq];
        v[4*qq+0] = a.x; v[4*qq+1] = a.y; v[4*qq+2] = a.z; v[4*qq+3] = a.w;
    }
#pragma unroll
    for (int j = 0; j < HID; ++j) v[j] = fmaxf(v[j] + bg[j], 0.0f);

    float lg[NC];
    float m = -1e30f;
#pragma unroll
    for (int cc = 0; cc < NC; ++cc) {
        float s = b2[cc];
#pragma unroll
        for (int j = 0; j < HID; ++j) s = fmaf(v[j], W2[cc * HID + j], s);
        lg[cc] = s;
        m = fmaxf(m, s);
    }
    float se = 0.0f;
#pragma unroll
    for (int cc = 0; cc < NC; ++cc) se += expf(lg[cc] - m);
    const float lse = m + logf(se);

    float4* op = (float4*)(out + (size_t)n * NC);
#pragma unroll
    for (int qq = 0; qq < NC / 4; ++qq)
        op[qq] = make_float4(lg[4*qq+0] - lse, lg[4*qq+1] - lse,
                             lg[4*qq+2] - lse, lg[4*qq+3] - lse);
}

// ---------------------------------------------------------------- launch ----
extern "C" void kernel_launch(void* const* d_in, const int* in_sizes, int n_in,
                              void* d_out, int out_size, void* d_ws, size_t ws_size,
                              hipStream_t stream) {
    const float* x   = (const float*)d_in[0];
    const int*   ei  = (const int*)d_in[1];     // [2, NE] int32
    const float* W1  = (const float*)d_in[2];
    const float* b1  = (const float*)d_in[3];
    const float* Wg  = (const float*)d_in[4];
    const float* bg  = (const float*)d_in[5];
    const float* W2  = (const float*)d_in[6];
    const float* b2  = (const float*)d_in[7];
    float*       out = (float*)d_out;

    const int* esrc = ei;
    const int* edst = ei + NE;

    // ws layout (4B units, 16B-aligned regions):
    //   hs[NN*16] | buf[NB*CAP] | dinv[NN] | gcur[NB]   ~ 21.2 MB total
    float*    hs   = (float*)d_ws;
    unsigned* buf  = (unsigned*)(hs + (size_t)NN * HID);
    float*    dinv = (float*)(buf + (size_t)NB * CAP);
    unsigned* gcur = (unsigned*)(dinv + NN);

    const int nodeBlocks = (NN + 255) / 256;        // 391
    const int h2Blocks   = (NN + 63) / 64;          // 1563

    k_initgcur<<<(NB + 255) / 256, 256, 0, stream>>>(gcur);
    k_bin<<<GRID_A, 256, 0, stream>>>(esrc, edst, gcur, buf);
    k_deg<<<NB, 256, 0, stream>>>(gcur, buf, dinv);
    k_h2<<<h2Blocks, 256, 0, stream>>>(x, W1, b1, Wg, dinv, hs);
    k_agg<<<NB, 256, 0, stream>>>(gcur, buf, dinv, hs);
    k_final<<<nodeBlocks, 256, 0, stream>>>((const float*)buf, bg, W2, b2, out);
}